// Round 1
// baseline (218.910 us; speedup 1.0000x reference)
//
#include <hip/hip_runtime.h>
#include <hip/hip_bf16.h>
#include <stdint.h>

typedef __bf16 bf16_t;
typedef __bf16 bf16x8 __attribute__((ext_vector_type(8)));
typedef __bf16 bf16x4 __attribute__((ext_vector_type(4)));
typedef float f32x4 __attribute__((ext_vector_type(4)));
typedef float f32x16 __attribute__((ext_vector_type(16)));
typedef uint32_t u32x4 __attribute__((ext_vector_type(4)));

#define XN 2097152   // x elements (2*1024*1024)
#define WN 1048576   // each weight (1024*1024)

static __device__ __forceinline__ uint16_t bfbits(float f) {
    bf16_t b = (bf16_t)f;
    return __builtin_bit_cast(uint16_t, b);
}

// ---------------- cast f32 -> bf16, all inputs fused ----------------
__global__ void cast_all_k(const float* __restrict__ x,
    const float* __restrict__ w0, const float* __restrict__ w1, const float* __restrict__ w2,
    const float* __restrict__ w3, const float* __restrict__ w4, const float* __restrict__ w5,
    const float* __restrict__ w6, bf16_t* __restrict__ dst)
{
    const int TOTC = (XN + 7 * WN) / 4;
    for (int c = blockIdx.x * blockDim.x + threadIdx.x; c < TOTC; c += gridDim.x * blockDim.x) {
        int el = c * 4;
        const float* s;
        if (el < XN) {
            s = x + el;
        } else {
            int r = el - XN;
            int wi = r >> 20;
            int off = r & (WN - 1);
            const float* wp = (wi == 0) ? w0 : (wi == 1) ? w1 : (wi == 2) ? w2
                             : (wi == 3) ? w3 : (wi == 4) ? w4 : (wi == 5) ? w5 : w6;
            s = wp + off;
        }
        float4 f = *(const float4*)s;
        bf16x4 o = { (bf16_t)f.x, (bf16_t)f.y, (bf16_t)f.z, (bf16_t)f.w };
        *(bf16x4*)(dst + el) = o;
    }
}

// ---------------- 128x128 bf16 MFMA GEMM: C = A @ W^T + bias ----------------
// A: (2048,1024) bf16 row-major; W: (1024,1024) bf16 row-major (out,in)
// EPI 0: bf16 natural out. EPI 1: z<2 bf16 natural, z==2 writes V^T layout
//        vT[((c*2+b)*16+h)*1024 + s]. EPI 2: f32 natural out.
template<int EPI>
__global__ __launch_bounds__(256)
void gemm128(const bf16_t* __restrict__ A0, const bf16_t* __restrict__ A1, const bf16_t* __restrict__ A2,
             const bf16_t* __restrict__ W0, const bf16_t* __restrict__ W1, const bf16_t* __restrict__ W2,
             const float* __restrict__ bias0, const float* __restrict__ bias1, const float* __restrict__ bias2,
             void* O0, void* O1, void* O2)
{
    const int z = blockIdx.z;
    const bf16_t* A = (z == 0) ? A0 : (z == 1) ? A1 : A2;
    const bf16_t* W = (z == 0) ? W0 : (z == 1) ? W1 : W2;
    const float* bias = (z == 0) ? bias0 : (z == 1) ? bias1 : bias2;
    void* Ov = (z == 0) ? O0 : (z == 1) ? O1 : O2;

    // +8 bf16 pad -> row stride 144B = 9*16B chunks: conflict-free-ish b128 reads
    __shared__ bf16_t As[128][72];
    __shared__ bf16_t Bs[128][72];

    const int tid = threadIdx.x;
    const int lane = tid & 63, wave = tid >> 6;
    const int lo = lane & 15, hi = lane >> 4;
    const int wr = wave >> 1, wc = wave & 1;
    const int m0 = blockIdx.y * 128, n0 = blockIdx.x * 128;

    f32x4 acc[4][4] = {};

    for (int kt = 0; kt < 16; ++kt) {
        const int K0 = kt * 64;
        bf16x8 ra[4], rb[4];
#pragma unroll
        for (int i = 0; i < 4; ++i) {
            int cid = tid + i * 256;
            int row = cid >> 3, ko = cid & 7;
            ra[i] = *(const bf16x8*)(A + (size_t)(m0 + row) * 1024 + K0 + ko * 8);
            rb[i] = *(const bf16x8*)(W + (size_t)(n0 + row) * 1024 + K0 + ko * 8);
        }
        __syncthreads();   // previous tile fully consumed
#pragma unroll
        for (int i = 0; i < 4; ++i) {
            int cid = tid + i * 256;
            int row = cid >> 3, ko = cid & 7;
            *(bf16x8*)&As[row][ko * 8] = ra[i];
            *(bf16x8*)&Bs[row][ko * 8] = rb[i];
        }
        __syncthreads();
#pragma unroll
        for (int kk = 0; kk < 2; ++kk) {
            const int kb = kk * 32 + hi * 8;
            bf16x8 af[4], bfr[4];
#pragma unroll
            for (int m = 0; m < 4; ++m) af[m] = *(const bf16x8*)&As[wr * 64 + m * 16 + lo][kb];
#pragma unroll
            for (int n = 0; n < 4; ++n) bfr[n] = *(const bf16x8*)&Bs[wc * 64 + n * 16 + lo][kb];
#pragma unroll
            for (int m = 0; m < 4; ++m)
#pragma unroll
                for (int n = 0; n < 4; ++n)
                    acc[m][n] = __builtin_amdgcn_mfma_f32_16x16x32_bf16(af[m], bfr[n], acc[m][n], 0, 0, 0);
        }
    }

#pragma unroll
    for (int n = 0; n < 4; ++n) {
        const int col = n0 + wc * 64 + n * 16 + lo;
        const float bv = bias[col];
#pragma unroll
        for (int m = 0; m < 4; ++m) {
            const int r0 = m0 + wr * 64 + m * 16 + hi * 4;
            if (EPI == 2) {
                float* O = (float*)Ov;
#pragma unroll
                for (int r = 0; r < 4; ++r)
                    O[(size_t)(r0 + r) * 1024 + col] = acc[m][n][r] + bv;
            } else if (EPI == 0 || z < 2) {
                bf16_t* O = (bf16_t*)Ov;
#pragma unroll
                for (int r = 0; r < 4; ++r)
                    O[(size_t)(r0 + r) * 1024 + col] = (bf16_t)(acc[m][n][r] + bv);
            } else {
                // V^T epilogue: col -> (c = col>>4, h = col&15); row -> (b = r0>>10, s = r0&1023)
                bf16_t* O = (bf16_t*)Ov;
                int cch = col >> 4, h = col & 15;
                int bb = r0 >> 10, ss = r0 & 1023;
                bf16x4 pv = { (bf16_t)(acc[m][n][0] + bv), (bf16_t)(acc[m][n][1] + bv),
                              (bf16_t)(acc[m][n][2] + bv), (bf16_t)(acc[m][n][3] + bv) };
                *(bf16x4*)(O + ((size_t)((cch * 2 + bb) * 16 + h)) * 1024 + ss) = pv;
            }
        }
    }
}

// ---------------- attention: per (c,b), 32x32x16 MFMA, swapped operands ----------------
// S^T = K·Q^T (K-dim = head_dim 16, dense). softmax without max-sub (scores ~ +-1).
// P^T B-fragments for O^T = V^T·P^T built in-register via pack + shfl_xor(32).
__global__ __launch_bounds__(256)
void attn_k(const bf16_t* __restrict__ qg, const bf16_t* __restrict__ kg,
            const bf16_t* __restrict__ vtg, bf16_t* __restrict__ y)
{
    const int c = blockIdx.y, b = blockIdx.z;
    const int lane = threadIdx.x & 63, wave = threadIdx.x >> 6;
    const int l31 = lane & 31, hi = lane >> 5;
    const int s = blockIdx.x * 128 + wave * 32 + l31;   // q row owned by this lane (as MFMA col)

    // Q fragment (B operand): B[k=h][n=q], per lane 16B contiguous
    bf16x8 qf = *(const bf16x8*)(qg + ((size_t)(b * 1024 + s)) * 1024 + c * 16 + hi * 8);
    const bf16_t* kbase = kg + ((size_t)b * 1024) * 1024 + c * 16 + hi * 8;
    const bf16_t* vbase = vtg + ((size_t)((c * 2 + b) * 16 + (lane & 15))) * 1024 + hi * 8;

    f32x16 oacc = {};
    const f32x16 zero16 = {};
    float den = 0.f;

    for (int jt = 0; jt < 32; ++jt) {
        // A operand: K rows j = jt*32 + l31, k = h
        bf16x8 kf = *(const bf16x8*)(kbase + (size_t)(jt * 32 + l31) * 1024);
        f32x16 st = __builtin_amdgcn_mfma_f32_32x32x16_bf16(kf, qf, zero16, 0, 0, 0);

        float p[16];
#pragma unroll
        for (int r = 0; r < 16; ++r) { p[r] = __expf(st[r] * 0.25f); den += p[r]; }

        uint32_t pk[8];
#pragma unroll
        for (int w = 0; w < 8; ++w)
            pk[w] = (uint32_t)bfbits(p[2 * w]) | ((uint32_t)bfbits(p[2 * w + 1]) << 16);
        uint32_t sp[8];
#pragma unroll
        for (int w = 0; w < 8; ++w) sp[w] = (uint32_t)__shfl_xor((int)pk[w], 32, 64);

        // Assemble P^T B-fragments for j-subtiles [0,16) and [16,32)
        uint32_t a0, a1, a2, a3, b0, b1, b2, b3;
        if (hi) {
            a0 = sp[2]; a1 = sp[3]; a2 = pk[2]; a3 = pk[3];
            b0 = sp[6]; b1 = sp[7]; b2 = pk[6]; b3 = pk[7];
        } else {
            a0 = pk[0]; a1 = pk[1]; a2 = sp[0]; a3 = sp[1];
            b0 = pk[4]; b1 = pk[5]; b2 = sp[4]; b3 = sp[5];
        }
        u32x4 f0v = { a0, a1, a2, a3 };
        u32x4 f1v = { b0, b1, b2, b3 };
        bf16x8 pf0 = __builtin_bit_cast(bf16x8, f0v);
        bf16x8 pf1 = __builtin_bit_cast(bf16x8, f1v);

        bf16x8 vf0 = *(const bf16x8*)(vbase + jt * 32);
        bf16x8 vf1 = *(const bf16x8*)(vbase + jt * 32 + 16);
        oacc = __builtin_amdgcn_mfma_f32_32x32x16_bf16(vf0, pf0, oacc, 0, 0, 0);
        oacc = __builtin_amdgcn_mfma_f32_32x32x16_bf16(vf1, pf1, oacc, 0, 0, 0);
    }

    float dtot = den + __shfl_xor(den, 32, 64);
    float rinv = 1.0f / dtot;

    // scatter into y with the torch-reshape permutation
    const int bo = (c >> 1) & 1;
    const int so = (c & 1) * 512 + b * 256 + (s >> 2);
    const int f0i = (c >> 2) * 64 + (s & 3) * 16;
    bf16_t* yb = y + ((size_t)bo * 1024 + so) * 1024 + f0i + 4 * hi;
    bf16x4 o1 = { (bf16_t)(oacc[0] * rinv), (bf16_t)(oacc[1] * rinv),
                  (bf16_t)(oacc[2] * rinv), (bf16_t)(oacc[3] * rinv) };
    *(bf16x4*)(yb) = o1;
    bf16x4 o2 = { (bf16_t)(oacc[4] * rinv), (bf16_t)(oacc[5] * rinv),
                  (bf16_t)(oacc[6] * rinv), (bf16_t)(oacc[7] * rinv) };
    *(bf16x4*)(yb + 8) = o2;
}

extern "C" void kernel_launch(void* const* d_in, const int* in_sizes, int n_in,
                              void* d_out, int out_size, void* d_ws, size_t ws_size,
                              hipStream_t stream)
{
    (void)in_sizes; (void)n_in; (void)out_size; (void)ws_size;
    const float* x    = (const float*)d_in[0];
    const float* wq_b = (const float*)d_in[2];
    const float* wk_b = (const float*)d_in[4];
    const float* wv_b = (const float*)d_in[6];
    const float* vq_b = (const float*)d_in[8];
    const float* vk_b = (const float*)d_in[10];
    const float* vv_b = (const float*)d_in[12];
    const float* wo_b = (const float*)d_in[14];

    bf16_t* base = (bf16_t*)d_ws;
    bf16_t* xbf = base;                 // 2,097,152
    bf16_t* wbf = base + XN;            // 7 x 1,048,576 (wq,wk,wv,vq,vk,vv,wo)
    bf16_t* q1  = base + XN + 7 * WN;
    bf16_t* k1  = q1 + XN;
    bf16_t* v1  = k1 + XN;
    bf16_t* q   = v1 + XN;
    bf16_t* k   = q + XN;
    bf16_t* vT  = k + XN;
    bf16_t* y   = q1;                   // q1 dead after stage 2 -> reuse for y

    cast_all_k<<<dim3(2048), dim3(256), 0, stream>>>(
        x, (const float*)d_in[1], (const float*)d_in[3], (const float*)d_in[5],
        (const float*)d_in[7], (const float*)d_in[9], (const float*)d_in[11],
        (const float*)d_in[13], base);

    // stage 1: q1/k1/v1 = x @ {wq,wk,wv}^T + b
    gemm128<0><<<dim3(8, 16, 3), dim3(256), 0, stream>>>(
        xbf, xbf, xbf, wbf, wbf + WN, wbf + 2 * WN,
        wq_b, wk_b, wv_b, q1, k1, v1);

    // stage 2: q/k = (q1/k1) @ {vq,vk}^T + b ; vT = transposed-layout v
    gemm128<1><<<dim3(8, 16, 3), dim3(256), 0, stream>>>(
        q1, k1, v1, wbf + 3 * WN, wbf + 4 * WN, wbf + 5 * WN,
        vq_b, vk_b, vv_b, q, k, vT);

    // attention + permuted scatter into y
    attn_k<<<dim3(8, 64, 2), dim3(256), 0, stream>>>(q, k, vT, y);

    // stage 3: out = y @ wo^T + b (f32)
    gemm128<2><<<dim3(8, 16, 1), dim3(256), 0, stream>>>(
        y, y, y, wbf + 6 * WN, wbf + 6 * WN, wbf + 6 * WN,
        wo_b, wo_b, wo_b, d_out, d_out, d_out);
}